// Round 19
// baseline (728.937 us; speedup 1.0000x reference)
//
#include <hip/hip_runtime.h>
#include <hip/hip_fp16.h>
#include <math.h>

typedef unsigned int uint;
typedef __fp16 half2_t __attribute__((ext_vector_type(2)));
typedef _Float16 v8h __attribute__((ext_vector_type(8)));
typedef _Float16 v4h __attribute__((ext_vector_type(4)));
typedef float f32v4 __attribute__((ext_vector_type(4)));

#define NUM_P 3
#define NUM_N 50000
#define NUM_C 5
#define NUM_E 150000
#define CF 340
#define NB32 1563               // ceil(N/32)
#define TE 96                   // edges per edge block (3 m-tiles/wave)
#define EB2 1563                // ceil(E/TE)
#define EST 36                  // edge LDS row stride (uints, 16B-aligned)
#define TN 128                  // nodes per node block
#define NB128 391               // ceil(N/TN)
#define SROW 129                // odd LDS row stride (fallback node kernel)
#define NSB 196                 // scan blocks per plane (ceil(N/256))
#define NSBP 50176              // NSB*256
#define NST 44                  // node_mfma LDS row stride (uints)

// ---- sizes (uint units) ----
#define AH_T   ((size_t)NUM_P * NUM_N * 170)     // aggr_h / xh / xn: 25,500,000
#define NW1_T  (NUM_P * NUM_C * 68 * 64)         // 65,280
#define NW2_T  (NUM_P * NUM_C * 32 * 64)         // 30,720
#define LG_T   ((size_t)NUM_P * NUM_C * NUM_E)   // 2,250,000
#define EWB_T  (NUM_P * NUM_C * 2 * 4 * 640)     // 76,800 mfma-frag weights

__device__ __forceinline__ float fast_tanh(float x) {
    float a = __expf(2.0f * x);
    float t = __builtin_amdgcn_rcpf(a + 1.0f);
    return fmaf(-2.0f, t, 1.0f);
}

__device__ __forceinline__ float dot2f(half2_t a, half2_t b, float c) {
#if __has_builtin(__builtin_amdgcn_fdot2)
    return __builtin_amdgcn_fdot2(a, b, c, false);
#else
    return fmaf((float)a[0], (float)b[0], fmaf((float)a[1], (float)b[1], c));
#endif
}

__device__ __forceinline__ half2_t bc(uint u) { return __builtin_bit_cast(half2_t, u); }

__device__ __forceinline__ uint pk2(float a, float b) {
    half2_t h = __builtin_amdgcn_cvt_pkrtz(a, b);
    return __builtin_bit_cast(uint, h);
}

__device__ __forceinline__ v8h mk8(uint a, uint b, uint c, uint d) {
    uint4 u; u.x = a; u.y = b; u.z = c; u.w = d;
    return __builtin_bit_cast(v8h, u);
}

// ---------------------------------------------------------------------------
// Transpose x -> xh [P][C][N][34] (class-major) + xn [P][N][170], f16 pairs.
// ---------------------------------------------------------------------------
__global__ __launch_bounds__(256) void convert_x_kernel(
    const float4* __restrict__ x4, uint* __restrict__ xh,
    uint* __restrict__ xn, int write_xn)
{
    __shared__ uint lds[32 * 170];
    const int nb = blockIdx.x % NB32;
    const int p  = blockIdx.x / NB32;
    const int n0 = nb * 32;
    const int nvalid = (n0 + 32 <= NUM_N) ? 32 : (NUM_N - n0);
    const int t = threadIdx.x;

    const float4* src = x4 + ((size_t)p * NUM_N + n0) * 85;
    const int nf4 = nvalid * 85;
    #pragma unroll
    for (int it = 0; it < 11; ++it) {
        const int i = t + it * 256;
        if (i < nf4) {
            const float4 v = src[i];
            lds[2 * i]     = pk2(v.x, v.y);
            lds[2 * i + 1] = pk2(v.z, v.w);
        }
    }
    __syncthreads();

    const int nq = nvalid * 34;
    #pragma unroll 1
    for (int c = 0; c < NUM_C; ++c) {
        uint* dst = xh + ((size_t)(p * NUM_C + c) * NUM_N + n0) * 34;
        #pragma unroll
        for (int it = 0; it < 5; ++it) {
            const int i = t + it * 256;
            if (i < nq) {
                const int nl = i / 34, j = i - nl * 34;
                dst[i] = lds[nl * 170 + c * 34 + j];
            }
        }
    }

    if (write_xn) {
        uint* dstn = xn + ((size_t)p * NUM_N + n0) * 170;
        const int tot = nvalid * 170;
        #pragma unroll
        for (int it = 0; it < 22; ++it) {
            const int i = t + it * 256;
            if (i < tot) dstn[i] = lds[i];
        }
    }
}

// pair-major weight pack: out[t*64+o] = (w[2t][o], w[2t+1][o])
__global__ __launch_bounds__(256) void pack_pairs_kernel(
    const float* __restrict__ in, uint* __restrict__ outp, int total)
{
    int i = blockIdx.x * 256 + threadIdx.x;
    if (i >= total) return;
    int t = i >> 6, o = i & 63;
    outp[i] = pk2(in[t * 128 + o], in[t * 128 + 64 + o]);
}

// ---------------------------------------------------------------------------
// Edge-weight pack into MFMA B-fragment linear order (unchanged).
// ---------------------------------------------------------------------------
__global__ __launch_bounds__(256) void pack_edge_mfma_kernel(
    const float* __restrict__ ew1, uint* __restrict__ ewb)
{
    int i = blockIdx.x * 256 + threadIdx.x;
    if (i >= EWB_T) return;
    int g    = i / 5120;
    int rem  = i - g * 5120;
    int s    = rem / 2560;
    int rem2 = rem - s * 2560;
    int nt   = rem2 / 640;
    int u    = rem2 - nt * 640;

    int f0, o; bool valid;
    if (u < 512) {
        int kt = u >> 8, uu = u & 255;
        int lane = uu >> 2, pp = uu & 3;
        f0 = kt * 32 + (lane >> 4) * 8 + 2 * pp;
        o  = nt * 16 + (lane & 15);
        valid = true;
    } else {
        int uu = u - 512;
        int lane = uu >> 1, pp = uu & 1;
        f0 = 64 + (lane >> 4) * 4 + 2 * pp;
        o  = nt * 16 + (lane & 15);
        valid = ((lane >> 4) == 0);
    }
    float w0 = 0.f, w1 = 0.f;
    if (valid) {
        int f = s * 68 + f0;
        w0 = ew1[((size_t)g * 136 + f) * 64 + o];
        w1 = ew1[((size_t)g * 136 + f + 1) * 64 + o];
    }
    ewb[i] = pk2(w0, w1);
}

// ---------------------------------------------------------------------------
// Edge MLP via MFMA, round-16 structure, TE=96 / stride 36 / predicated A2.
// ---------------------------------------------------------------------------
__global__ __launch_bounds__(128) void edge_mfma_kernel(
    const uint*  __restrict__ xh,       // [P*C][N][34]
    const int*   __restrict__ ei,       // [P][2][E]      (ei mode)
    const int*   __restrict__ csr_src,  // [P][E]         (csr mode)
    const int*   __restrict__ csr_dst,  // [P][E]         (csr mode)
    const uint*  __restrict__ ewb,
    const float* __restrict__ eb1,
    const float* __restrict__ ew2,
    const float* __restrict__ eb2,
    float*       __restrict__ logits,   // [g][E] indexed by pos (csr) or e (ei)
    int use_csr)
{
    __shared__ uint smem[TE * EST];
    __shared__ int  ids[2][TE];

    const int g    = blockIdx.x / EB2;
    const int blk  = blockIdx.x - g * EB2;
    const int p    = g / NUM_C;
    const int e0   = blk * TE;
    const int t    = threadIdx.x;
    const int lane = t & 63;
    const int wv   = t >> 6;
    const int col  = lane & 15;
    const int G    = lane >> 4;

    if (t < TE) {
        const int e  = e0 + t;
        const int ec = (e < NUM_E) ? e : (NUM_E - 1);
        if (use_csr) {
            ids[0][t] = csr_src[(size_t)p * NUM_E + ec];   // src (x_j)
            ids[1][t] = csr_dst[(size_t)p * NUM_E + ec];   // dst (x_i)
        } else {
            ids[0][t] = ei[(p * 2 + 0) * NUM_E + ec];
            ids[1][t] = ei[(p * 2 + 1) * NUM_E + ec];
        }
    }

    const uint* slice = xh + (size_t)g * NUM_N * 34;

    float b1v[4], w2v[4];
    #pragma unroll
    for (int nt = 0; nt < 4; ++nt) {
        b1v[nt] = eb1[g * 64 + nt * 16 + col];
        w2v[nt] = ew2[g * 64 + nt * 16 + col];
    }

    f32v4 acc[3][4];
    #pragma unroll
    for (int m = 0; m < 3; ++m)
        #pragma unroll
        for (int nt = 0; nt < 4; ++nt) {
            f32v4 a = {b1v[nt], b1v[nt], b1v[nt], b1v[nt]};
            acc[m][nt] = a;
        }
    __syncthreads();   // ids visible

    #pragma unroll 1
    for (int side = 0; side < 2; ++side) {
        // ---- stage: 96 rows x 17 uint2, row-major [e][EST] ----
        const int* idr = ids[1 - side];            // side0 = x_i(dst), side1 = x_j(src)
        #pragma unroll
        for (int k = 0; k < 13; ++k) {
            const int i2 = t + 128 * k;
            if (i2 < TE * 17) {
                const int e  = i2 / 17, j2 = i2 - e * 17;
                const uint2 v = *(const uint2*)(slice + (size_t)idr[e] * 34 + 2 * j2);
                *(uint2*)&smem[e * EST + 2 * j2] = v;
            }
        }
        __syncthreads();

        // ---- B fragments for this side (global, L2-hot) ----
        const uint* wb = ewb + (size_t)((g * 2 + side) * 4) * 640;
        v8h B0[4], B1[4]; v4h B2[4];
        #pragma unroll
        for (int nt = 0; nt < 4; ++nt) {
            const uint* fb = wb + nt * 640;
            B0[nt] = __builtin_bit_cast(v8h, *(const uint4*)(fb + lane * 4));
            B1[nt] = __builtin_bit_cast(v8h, *(const uint4*)(fb + 256 + lane * 4));
            B2[nt] = __builtin_bit_cast(v4h, *(const uint2*)(fb + 512 + lane * 2));
        }

        // ---- MFMA: 3 mtiles x 4 ntiles x (2x K32 + 1x K16) ----
        #pragma unroll
        for (int m = 0; m < 3; ++m) {
            const uint* rp = &smem[(wv * 48 + m * 16 + col) * EST];
            const v8h A0 = __builtin_bit_cast(v8h, *(const uint4*)(rp + G * 4));
            const v8h A1 = __builtin_bit_cast(v8h, *(const uint4*)(rp + 16 + G * 4));
            v4h A2 = {};                           // K-tail: only G==0 holds real
            if (G == 0)                            // features 64..67; B2==0 for G>0
                A2 = __builtin_bit_cast(v4h, *(const uint2*)(rp + 32));
            #pragma unroll
            for (int nt = 0; nt < 4; ++nt) {
                acc[m][nt] = __builtin_amdgcn_mfma_f32_16x16x32_f16(A0, B0[nt], acc[m][nt], 0, 0, 0);
                acc[m][nt] = __builtin_amdgcn_mfma_f32_16x16x32_f16(A1, B1[nt], acc[m][nt], 0, 0, 0);
                acc[m][nt] = __builtin_amdgcn_mfma_f32_16x16x16f16(A2, B2[nt], acc[m][nt], 0, 0, 0);
            }
        }
        __syncthreads();   // all reads done before next-side overwrite / elds
    }

    // ---- epilogue: logit = sum_o w2[o]*tanh(h[e][o]) + eb2 ----
    float* elds = (float*)smem;                    // [96][20] f32
    #pragma unroll
    for (int m = 0; m < 3; ++m) {
        #pragma unroll
        for (int r = 0; r < 4; ++r) {
            float part = 0.f;
            #pragma unroll
            for (int nt = 0; nt < 4; ++nt)
                part = fmaf(w2v[nt], fast_tanh(acc[m][nt][r]), part);
            elds[(wv * 48 + m * 16 + G * 4 + r) * 20 + col] = part;
        }
    }
    __syncthreads();   // rows cross waves at TE=96
    if (t < TE && e0 + t < NUM_E) {
        const float4 s0 = *(const float4*)&elds[t * 20 + 0];
        const float4 s1 = *(const float4*)&elds[t * 20 + 4];
        const float4 s2 = *(const float4*)&elds[t * 20 + 8];
        const float4 s3 = *(const float4*)&elds[t * 20 + 12];
        float lg = ((s0.x + s0.y) + (s0.z + s0.w)) + ((s1.x + s1.y) + (s1.z + s1.w))
                 + ((s2.x + s2.y) + (s2.z + s2.w)) + ((s3.x + s3.y) + (s3.z + s3.w))
                 + eb2[g];
        logits[(size_t)g * NUM_E + e0 + t] = lg;
    }
}

// ---------------------------------------------------------------------------
// Per-edge softmax: thread = (p,pos) -> wbuf[P][C][E].
// ---------------------------------------------------------------------------
__global__ __launch_bounds__(256) void softmax_kernel(
    const float* __restrict__ logits, float* __restrict__ wbuf)
{
    const int i = blockIdx.x * 256 + threadIdx.x;
    if (i >= NUM_P * NUM_E) return;
    const int p = i / NUM_E, e = i - p * NUM_E;
    const size_t base = (size_t)p * NUM_C * NUM_E + e;
    float l[NUM_C];
    #pragma unroll
    for (int c = 0; c < NUM_C; ++c) l[c] = logits[base + (size_t)c * NUM_E];
    float m = l[0];
    #pragma unroll
    for (int c = 1; c < NUM_C; ++c) m = fmaxf(m, l[c]);
    float s = 0.f;
    #pragma unroll
    for (int c = 0; c < NUM_C; ++c) { l[c] = __expf(l[c] - m); s += l[c]; }
    const float inv = __builtin_amdgcn_rcpf(s);
    #pragma unroll
    for (int c = 0; c < NUM_C; ++c) wbuf[base + (size_t)c * NUM_E] = l[c] * inv;
}

// ---------------------------------------------------------------------------
// CSR build.
// ---------------------------------------------------------------------------
__global__ __launch_bounds__(256) void deg_kernel(
    const int* __restrict__ ei, int* __restrict__ deg)
{
    const int i = blockIdx.x * 256 + threadIdx.x;
    if (i >= NUM_P * NUM_E) return;
    const int p = i / NUM_E, e = i - p * NUM_E;
    const int dst = ei[(p * 2 + 1) * NUM_E + e];
    atomicAdd(&deg[p * NUM_N + dst], 1);
}

__global__ __launch_bounds__(256) void scan_block_kernel(
    const int* __restrict__ deg, int* __restrict__ intra, int* __restrict__ bsum)
{
    __shared__ int s[256];
    const int blk = blockIdx.x % NSB;
    const int p   = blockIdx.x / NSB;
    const int t   = threadIdx.x;
    const int n   = blk * 256 + t;
    const int d   = (n < NUM_N) ? deg[p * NUM_N + n] : 0;
    s[t] = d;
    __syncthreads();
    #pragma unroll
    for (int o = 1; o < 256; o <<= 1) {
        int v = (t >= o) ? s[t - o] : 0;
        __syncthreads();
        s[t] += v;
        __syncthreads();
    }
    if (n < NUM_N) intra[p * NSBP + n] = s[t] - d;
    if (t == 255) bsum[p * NSB + blk] = s[255];
}

__global__ __launch_bounds__(256) void scan_seg_kernel(
    const int* __restrict__ bsum, int* __restrict__ segoff)
{
    __shared__ int s[256];
    const int t = threadIdx.x;
    #pragma unroll 1
    for (int p = 0; p < NUM_P; ++p) {
        const int b = (t < NSB) ? bsum[p * NSB + t] : 0;
        s[t] = b;
        __syncthreads();
        #pragma unroll
        for (int o = 1; o < 256; o <<= 1) {
            int v = (t >= o) ? s[t - o] : 0;
            __syncthreads();
            s[t] += v;
            __syncthreads();
        }
        if (t < NSB) segoff[p * NSB + t] = s[t] - b;
        __syncthreads();
    }
}

__global__ __launch_bounds__(256) void fill_kernel(
    const int* __restrict__ ei, int* __restrict__ cursor,
    const int* __restrict__ intra, const int* __restrict__ segoff,
    int* __restrict__ csr_src, int* __restrict__ csr_dst)
{
    const int i = blockIdx.x * 256 + threadIdx.x;
    if (i >= NUM_P * NUM_E) return;
    const int p = i / NUM_E, e = i - p * NUM_E;
    const int src = ei[(p * 2 + 0) * NUM_E + e];
    const int dst = ei[(p * 2 + 1) * NUM_E + e];
    const int slot = atomicAdd(&cursor[p * NUM_N + dst], 1);
    const int pos  = segoff[p * NSB + (dst >> 8)] + intra[p * NSBP + dst] + slot;
    csr_src[(size_t)p * NUM_E + pos] = src;
    csr_dst[(size_t)p * NUM_E + pos] = dst;
}

// ---------------------------------------------------------------------------
// Gather: wave per (p, dst-node); gate weights read SEQUENTIALLY by CSR pos.
// ---------------------------------------------------------------------------
__global__ __launch_bounds__(256) void gather_kernel(
    const uint*  __restrict__ xn,
    const float* __restrict__ wbuf,    // [P][C][E], indexed by pos
    const int*   __restrict__ csr_src,
    const int*   __restrict__ deg,
    const int*   __restrict__ intra,
    const int*   __restrict__ segoff,
    uint*        __restrict__ aggr)
{
    const int wslot = threadIdx.x >> 6;
    const int lane  = threadIdx.x & 63;
    const int gw = blockIdx.x * 4 + wslot;
    const int p  = gw / NUM_N;
    const int n  = gw - p * NUM_N;

    const int dg   = deg[p * NUM_N + n];
    const int off0 = segoff[p * NSB + (n >> 8)] + intra[p * NSBP + n];

    const int q1 = lane + 64, q2 = lane + 128;
    const int c0 = lane / 34;
    const int c1 = q1 / 34;
    const int c2 = q2 / 34;

    float a0 = 0.f, a1 = 0.f, a2 = 0.f, a3 = 0.f, a4 = 0.f, a5 = 0.f;

    #pragma unroll 1
    for (int d = 0; d < dg; ++d) {
        const int pos = off0 + d;
        const int src = csr_src[(size_t)p * NUM_E + pos];

        const float wa = wbuf[(size_t)(p * NUM_C + c0) * NUM_E + pos];
        const float wb = wbuf[(size_t)(p * NUM_C + c1) * NUM_E + pos];
        const float wc = (lane < 42) ? wbuf[(size_t)(p * NUM_C + c2) * NUM_E + pos] : 0.f;

        const uint* row = xn + (size_t)(p * NUM_N + src) * 170;
        const uint u0 = row[lane];
        const uint u1 = row[q1];
        const uint u2 = (lane < 42) ? row[q2] : 0u;
        const half2_t h0 = bc(u0), h1 = bc(u1), h2 = bc(u2);
        a0 = fmaf(wa, (float)h0[0], a0);
        a1 = fmaf(wa, (float)h0[1], a1);
        a2 = fmaf(wb, (float)h1[0], a2);
        a3 = fmaf(wb, (float)h1[1], a3);
        a4 = fmaf(wc, (float)h2[0], a4);
        a5 = fmaf(wc, (float)h2[1], a5);
    }

    const int i0 = lane - c0 * 34;
    const int i1 = q1 - c1 * 34;
    const int i2 = q2 - c2 * 34;
    aggr[((size_t)(p * NUM_C + c0) * NUM_N + n) * 34 + i0] = pk2(a0, a1);
    aggr[((size_t)(p * NUM_C + c1) * NUM_N + n) * 34 + i1] = pk2(a2, a3);
    if (lane < 42)
        aggr[((size_t)(p * NUM_C + c2) * NUM_N + n) * 34 + i2] = pk2(a4, a5);
}

// ---------------------------------------------------------------------------
// Fallback scatter (only if !fits). logits indexed by e (ei order).
// ---------------------------------------------------------------------------
__global__ __launch_bounds__(256) void edge_scatter_kernel(
    const uint*  __restrict__ xh,
    const int*   __restrict__ ei,
    const float* __restrict__ logits,
    uint*        __restrict__ aggr)
{
    const int wslot = threadIdx.x >> 6;
    const int lane  = threadIdx.x & 63;
    const int gw    = blockIdx.x * 4 + wslot;
    const int p     = gw / NUM_E;
    const int e     = gw - p * NUM_E;

    const int src = ei[(p * 2 + 0) * NUM_E + e];
    const int dst = ei[(p * 2 + 1) * NUM_E + e];

    float l[NUM_C];
    #pragma unroll
    for (int c = 0; c < NUM_C; ++c)
        l[c] = logits[(size_t)(p * NUM_C + c) * NUM_E + e];
    float m = l[0];
    #pragma unroll
    for (int c = 1; c < NUM_C; ++c) m = fmaxf(m, l[c]);
    float s = 0.f;
    #pragma unroll
    for (int c = 0; c < NUM_C; ++c) { l[c] = __expf(l[c] - m); s += l[c]; }
    const float inv = __builtin_amdgcn_rcpf(s);
    const float wt0 = l[0] * inv, wt1 = l[1] * inv, wt2 = l[2] * inv,
                wt3 = l[3] * inv, wt4 = l[4] * inv;

    #pragma unroll
    for (int k = 0; k < 3; ++k) {
        const int q = lane + 64 * k;
        if (q < 170) {
            const int c   = q / 34;
            const int idx = q - c * 34;
            const float wv = (c == 0) ? wt0 : (c == 1) ? wt1 : (c == 2) ? wt2
                           : (c == 3) ? wt3 : wt4;
            const uint xv = xh[((size_t)(p * NUM_C + c) * NUM_N + src) * 34 + idx];
            half2_t mv = __builtin_amdgcn_cvt_pkrtz(wv, wv) * bc(xv);
            uint* ap = aggr + ((size_t)(p * NUM_C + c) * NUM_N + dst) * 34 + idx;
            unsafeAtomicAdd((__half2*)ap, __builtin_bit_cast(__half2, mv));
        }
    }
}

// ---------------------------------------------------------------------------
// Node MLP via MFMA v2 (unchanged from round 16).
// ---------------------------------------------------------------------------
__global__ __launch_bounds__(256) void node_mfma_kernel(
    const uint*  __restrict__ xh,
    const uint*  __restrict__ aggr,
    const uint*  __restrict__ nwp,
    const uint*  __restrict__ n2p,
    const float* __restrict__ nb1,
    const float* __restrict__ nb2,
    float*       __restrict__ out)
{
    __shared__ uint smem[TN * NST];

    const int g    = blockIdx.x / NB128;
    const int blk  = blockIdx.x - g * NB128;
    const int p    = g / NUM_C;
    const int c    = g - p * NUM_C;
    const int n0   = blk * TN;
    const int t    = threadIdx.x;
    const int lane = t & 63;
    const int wv   = t >> 6;
    const int col  = lane & 15;
    const int G    = lane >> 4;
    const int nvalid = (n0 + TN <= NUM_N) ? TN : (NUM_N - n0);
    const int lim2   = nvalid * 17;

    if (t < TN) {
        const uint2 z = make_uint2(0u, 0u);
        *(uint2*)&smem[t * NST + 34] = z;
        *(uint2*)&smem[t * NST + 36] = z;
        *(uint2*)&smem[t * NST + 38] = z;
    }

    const uint* wgp = nwp + (size_t)g * 68 * 64;

    float b1v[4];
    #pragma unroll
    for (int nt = 0; nt < 4; ++nt) b1v[nt] = nb1[g * 64 + nt * 16 + col];

    f32v4 acc[2][4];
    #pragma unroll
    for (int mt = 0; mt < 2; ++mt)
        #pragma unroll
        for (int nt = 0; nt < 4; ++nt) {
            f32v4 a = {b1v[nt], b1v[nt], b1v[nt], b1v[nt]};
            acc[mt][nt] = a;
        }

    #pragma unroll 1
    for (int side = 0; side < 2; ++side) {
        const uint* srcp = (side == 0 ? xh : aggr) + ((size_t)g * NUM_N + n0) * 34;
        #pragma unroll
        for (int k = 0; k < 9; ++k) {
            const int i2 = t + 256 * k;
            if (i2 < TN * 17) {
                const int i2c = (i2 < lim2) ? i2 : (lim2 - 1);
                const uint2 v = *(const uint2*)(srcp + 2 * i2c);
                const int nl = i2 / 17, j2 = i2 - nl * 17;
                *(uint2*)&smem[nl * NST + 2 * j2] = v;
            }
        }
        __syncthreads();

        v8h B0[4], B1[4]; v4h B2[4];
        #pragma unroll
        for (int nt = 0; nt < 4; ++nt) {
            const int oc = nt * 16 + col;
            const int r0 = side * 34 + G * 4;
            B0[nt] = mk8(wgp[(r0 + 0) * 64 + oc], wgp[(r0 + 1) * 64 + oc],
                         wgp[(r0 + 2) * 64 + oc], wgp[(r0 + 3) * 64 + oc]);
            const int r1 = r0 + 16;
            B1[nt] = mk8(wgp[(r1 + 0) * 64 + oc], wgp[(r1 + 1) * 64 + oc],
                         wgp[(r1 + 2) * 64 + oc], wgp[(r1 + 3) * 64 + oc]);
            uint b2a = (G == 0) ? wgp[(side * 34 + 32) * 64 + oc] : 0u;
            uint b2b = (G == 0) ? wgp[(side * 34 + 33) * 64 + oc] : 0u;
            uint2 u2; u2.x = b2a; u2.y = b2b;
            B2[nt] = __builtin_bit_cast(v4h, u2);
        }

        #pragma unroll
        for (int mt = 0; mt < 2; ++mt) {
            const uint* rp = &smem[(wv * 32 + mt * 16 + col) * NST];
            const v8h A0 = __builtin_bit_cast(v8h, *(const uint4*)(rp + G * 4));
            const v8h A1 = __builtin_bit_cast(v8h, *(const uint4*)(rp + 16 + G * 4));
            const v4h A2 = __builtin_bit_cast(v4h, *(const uint2*)(rp + 32 + G * 2));
            #pragma unroll
            for (int nt = 0; nt < 4; ++nt) {
                acc[mt][nt] = __builtin_amdgcn_mfma_f32_16x16x32_f16(A0, B0[nt], acc[mt][nt], 0, 0, 0);
                acc[mt][nt] = __builtin_amdgcn_mfma_f32_16x16x32_f16(A1, B1[nt], acc[mt][nt], 0, 0, 0);
                acc[mt][nt] = __builtin_amdgcn_mfma_f32_16x16x16f16(A2, B2[nt], acc[mt][nt], 0, 0, 0);
            }
        }
        __syncthreads();
    }

    _Float16* hl = (_Float16*)smem;
    #pragma unroll
    for (int mt = 0; mt < 2; ++mt)
        #pragma unroll
        for (int nt = 0; nt < 4; ++nt)
            #pragma unroll
            for (int r = 0; r < 4; ++r)
                hl[(wv * 32 + mt * 16 + G * 4 + r) * 72 + nt * 16 + col] =
                    (_Float16)fast_tanh(acc[mt][nt][r]);

    const uint* w2p = n2p + (size_t)g * 32 * 64;
    float b2v[4];
    #pragma unroll
    for (int nt = 0; nt < 4; ++nt) b2v[nt] = nb2[g * 64 + nt * 16 + col];

    f32v4 acc2[2][4];
    #pragma unroll
    for (int mt = 0; mt < 2; ++mt)
        #pragma unroll
        for (int nt = 0; nt < 4; ++nt) {
            f32v4 a = {b2v[nt], b2v[nt], b2v[nt], b2v[nt]};
            acc2[mt][nt] = a;
        }

    v8h C0[4], C1[4];
    #pragma unroll
    for (int nt = 0; nt < 4; ++nt) {
        const int oc = nt * 16 + col;
        C0[nt] = mk8(w2p[(G * 4 + 0) * 64 + oc], w2p[(G * 4 + 1) * 64 + oc],
                     w2p[(G * 4 + 2) * 64 + oc], w2p[(G * 4 + 3) * 64 + oc]);
        C1[nt] = mk8(w2p[(16 + G * 4 + 0) * 64 + oc], w2p[(16 + G * 4 + 1) * 64 + oc],
                     w2p[(16 + G * 4 + 2) * 64 + oc], w2p[(16 + G * 4 + 3) * 64 + oc]);
    }

    #pragma unroll
    for (int mt = 0; mt < 2; ++mt) {
        const uint* rp = &smem[(wv * 32 + mt * 16 + col) * 36];
        const v8h A0 = __builtin_bit_cast(v8h, *(const uint4*)(rp + G * 4));
        const v8h A1 = __builtin_bit_cast(v8h, *(const uint4*)(rp + 16 + G * 4));
        #pragma unroll
        for (int nt = 0; nt < 4; ++nt) {
            acc2[mt][nt] = __builtin_amdgcn_mfma_f32_16x16x32_f16(A0, C0[nt], acc2[mt][nt], 0, 0, 0);
            acc2[mt][nt] = __builtin_amdgcn_mfma_f32_16x16x32_f16(A1, C1[nt], acc2[mt][nt], 0, 0, 0);
        }
    }
    __syncthreads();

    float* elds = (float*)smem;
    #pragma unroll
    for (int pass = 0; pass < 2; ++pass) {
        #pragma unroll
        for (int mt = 0; mt < 2; ++mt)
            #pragma unroll
            for (int r = 0; r < 4; ++r) {
                const int row = wv * 32 + mt * 16 + G * 4 + r;
                elds[row * NST + col]      = fast_tanh(acc2[mt][2 * pass][r]);
                elds[row * NST + 16 + col] = fast_tanh(acc2[mt][2 * pass + 1][r]);
            }
        const int row = wv * 32 + (lane >> 1);
        if (row < nvalid) {
            float* op = out + ((size_t)(p * NUM_N + n0 + row) * NUM_C + c) * 64
                      + pass * 32 + (lane & 1) * 16;
            const float* ep = &elds[row * NST + (lane & 1) * 16];
            #pragma unroll
            for (int q = 0; q < 4; ++q)
                *(float4*)(op + q * 4) = *(const float4*)(ep + q * 4);
        }
        if (pass == 0) __syncthreads();
    }
}

// ---------------------------------------------------------------------------
// Fallback node kernel (dot2, fp32 x path) — used only when !fits.
// ---------------------------------------------------------------------------
__device__ __forceinline__ void dot_side(const uint* __restrict__ xp,
                                         const uint* __restrict__ wp,
                                         float acc[64])
{
    uint2 cur = *(const uint2*)(xp);
    #pragma unroll 1
    for (int j = 0; j < 17; ++j) {
        const int jn = (j < 16) ? (j + 1) : 16;
        const uint2 nxt = *(const uint2*)(xp + jn * 2);
        const half2_t a0 = bc(cur.x);
        const half2_t a1 = bc(cur.y);
        const uint* w0 = wp + (2 * j) * 64;
        #pragma unroll
        for (int o = 0; o < 64; ++o)
            acc[o] = dot2f(a0, bc(w0[o]), acc[o]);
        const uint* w1 = w0 + 64;
        #pragma unroll
        for (int o = 0; o < 64; ++o)
            acc[o] = dot2f(a1, bc(w1[o]), acc[o]);
        cur = nxt;
    }
}

__global__ __launch_bounds__(128) void node_kernel(
    const float* __restrict__ x,
    const uint*  __restrict__ aggr,
    const uint*  __restrict__ nwp,
    const uint*  __restrict__ n2p,
    const float* __restrict__ nb1,
    const float* __restrict__ nb2,
    float*       __restrict__ out)
{
    __shared__ uint buf[34][SROW];

    const int g   = blockIdx.x / NB128;
    const int blk = blockIdx.x - g * NB128;
    const int p   = g / NUM_C;
    const int c   = g - p * NUM_C;
    const int n0  = blk * TN;
    const int t   = threadIdx.x;
    const int nvalid = (n0 + TN <= NUM_N) ? TN : (NUM_N - n0);
    const int lim2 = nvalid * 17;

    float acc[64];
    const float* b1 = nb1 + g * 64;
    #pragma unroll
    for (int o4 = 0; o4 < 64; o4 += 4) {
        const float4 bv = *(const float4*)(b1 + o4);
        acc[o4] = bv.x; acc[o4 + 1] = bv.y; acc[o4 + 2] = bv.z; acc[o4 + 3] = bv.w;
    }
    const uint* wg = nwp + (size_t)g * 68 * 64;

    #pragma unroll
    for (int k = 0; k < 34; ++k) {
        const int i  = t + TN * k;
        const int nl = i / 34, j = i - nl * 34;
        const int nn = (nl < nvalid) ? (n0 + nl) : n0;
        const float2 v = *(const float2*)(x + ((size_t)p * NUM_N + nn) * CF
                                          + c * 68 + 2 * j);
        buf[j][nl] = pk2(v.x, v.y);
    }
    __syncthreads();
    #pragma unroll 1
    for (int j = 0; j < 34; ++j) {
        const half2_t a = bc(buf[j][t]);
        const uint* w = wg + j * 64;
        #pragma unroll
        for (int o = 0; o < 64; ++o) acc[o] = dot2f(a, bc(w[o]), acc[o]);
    }
    __syncthreads();

    {
        const uint* srcp = aggr + ((size_t)g * NUM_N + n0) * 34;
        #pragma unroll
        for (int k = 0; k < 17; ++k) {
            const int i2  = t + TN * k;
            const int i2c = (i2 < lim2) ? i2 : (lim2 - 1);
            const uint2 v = *(const uint2*)(srcp + 2 * i2c);
            const int nl = i2 / 17, j2 = i2 - nl * 17;
            buf[2 * j2][nl]     = v.x;
            buf[2 * j2 + 1][nl] = v.y;
        }
    }
    __syncthreads();
    #pragma unroll 1
    for (int j = 0; j < 34; ++j) {
        const half2_t a = bc(buf[j][t]);
        const uint* w = wg + (34 + j) * 64;
        #pragma unroll
        for (int o = 0; o < 64; ++o) acc[o] = dot2f(a, bc(w[o]), acc[o]);
    }

    uint h2p[32];
    #pragma unroll
    for (int f2 = 0; f2 < 32; ++f2)
        h2p[f2] = pk2(fast_tanh(acc[2 * f2]), fast_tanh(acc[2 * f2 + 1]));

    const float* b2 = nb2 + g * 64;
    float acc2[64];
    #pragma unroll
    for (int o4 = 0; o4 < 64; o4 += 4) {
        const float4 bv = *(const float4*)(b2 + o4);
        acc2[o4] = bv.x; acc2[o4 + 1] = bv.y; acc2[o4 + 2] = bv.z; acc2[o4 + 3] = bv.w;
    }
    const uint* w2g = n2p + (size_t)g * 32 * 64;
    #pragma unroll
    for (int f2 = 0; f2 < 32; ++f2) {
        const half2_t hv = bc(h2p[f2]);
        const uint* wr = w2g + f2 * 64;
        #pragma unroll
        for (int o = 0; o < 64; ++o)
            acc2[o] = dot2f(hv, bc(wr[o]), acc2[o]);
    }

    if (t < nvalid) {
        float* op = out + ((size_t)(p * NUM_N + n0 + t) * NUM_C + c) * 64;
        #pragma unroll
        for (int o4 = 0; o4 < 64; o4 += 4) {
            float4 ov;
            ov.x = fast_tanh(acc2[o4 + 0]);
            ov.y = fast_tanh(acc2[o4 + 1]);
            ov.z = fast_tanh(acc2[o4 + 2]);
            ov.w = fast_tanh(acc2[o4 + 3]);
            *(float4*)(op + o4) = ov;
        }
    }
}

extern "C" void kernel_launch(void* const* d_in, const int* in_sizes, int n_in,
                              void* d_out, int out_size, void* d_ws, size_t ws_size,
                              hipStream_t stream)
{
    (void)in_sizes; (void)n_in; (void)out_size;

    const float* x   = (const float*)d_in[0];
    const int*   ei  = (const int*)  d_in[1];
    const float* ew1 = (const float*)d_in[2];
    const float* eb1 = (const float*)d_in[3];
    const float* ew2 = (const float*)d_in[4];
    const float* eb2 = (const float*)d_in[5];
    const float* nw1 = (const float*)d_in[6];
    const float* nb1 = (const float*)d_in[7];
    const float* nw2 = (const float*)d_in[8];
    const float* nb2 = (const float*)d_in[9];
    float*       out = (float*)d_out;

    // ws (uints): [aggr_h | nwp | n2p | xh]
    uint* ws     = (uint*)d_ws;
    uint* aggr_h = ws;
    uint* nwp    = ws + AH_T;
    uint* n2p    = nwp + NW1_T;
    const size_t o_xh = AH_T + NW1_T + NW2_T;
    const bool fits = ws_size >= (o_xh + AH_T) * sizeof(uint);
    uint*  xh     = fits ? (ws + o_xh) : (uint*)d_out;
    uint*  xn     = (uint*)d_out;
    float* logits = (float*)((uint*)d_out + AH_T);
    uint*  ewb    = (uint*)d_out + AH_T + LG_T;

    int* ibase   = (int*)(ewb + EWB_T);
    int* deg     = ibase;
    int* cursor  = ibase + NUM_P * NUM_N;
    int* intra   = cursor + NUM_P * NUM_N;
    int* bsum    = intra + NUM_P * NSBP;
    int* segoff  = bsum + NUM_P * NSB;
    int* csr_src = segoff + NUM_P * NSB;
    int* csr_dst = csr_src + NUM_P * NUM_E;
    float* wbuf  = (float*)(csr_dst + NUM_P * NUM_E);   // [P][C][E]

    convert_x_kernel<<<NUM_P * NB32, 256, 0, stream>>>(
        (const float4*)x, xh, xn, fits ? 1 : 0);
    pack_edge_mfma_kernel<<<(EWB_T + 255) / 256, 256, 0, stream>>>(ew1, ewb);
    pack_pairs_kernel<<<(NW1_T + 255) / 256, 256, 0, stream>>>(nw1, nwp, NW1_T);
    pack_pairs_kernel<<<(NW2_T + 255) / 256, 256, 0, stream>>>(nw2, n2p, NW2_T);

    if (fits) {
        (void)hipMemsetAsync(ibase, 0, (size_t)2 * NUM_P * NUM_N * sizeof(int), stream);
        const int egrid = (NUM_P * NUM_E + 255) / 256;
        deg_kernel<<<egrid, 256, 0, stream>>>(ei, deg);
        scan_block_kernel<<<NUM_P * NSB, 256, 0, stream>>>(deg, intra, bsum);
        scan_seg_kernel<<<1, 256, 0, stream>>>(bsum, segoff);
        fill_kernel<<<egrid, 256, 0, stream>>>(ei, cursor, intra, segoff,
                                               csr_src, csr_dst);

        edge_mfma_kernel<<<NUM_P * NUM_C * EB2, 128, 0, stream>>>(
            xh, ei, csr_src, csr_dst, ewb, eb1, ew2, eb2, logits, 1);
        softmax_kernel<<<egrid, 256, 0, stream>>>(logits, wbuf);
        gather_kernel<<<(NUM_P * NUM_N) / 4, 256, 0, stream>>>(
            xn, wbuf, csr_src, deg, intra, segoff, aggr_h);
        node_mfma_kernel<<<NUM_P * NUM_C * NB128, 256, 0, stream>>>(
            xh, aggr_h, nwp, n2p, nb1, nb2, out);
    } else {
        edge_mfma_kernel<<<NUM_P * NUM_C * EB2, 128, 0, stream>>>(
            xh, ei, (const int*)ei, (const int*)ei, ewb, eb1, ew2, eb2, logits, 0);
        (void)hipMemsetAsync(aggr_h, 0, AH_T * sizeof(uint), stream);
        edge_scatter_kernel<<<(NUM_P * NUM_E) / 4, 256, 0, stream>>>(
            xh, ei, logits, aggr_h);
        node_kernel<<<NUM_P * NUM_C * NB128, 128, 0, stream>>>(
            x, aggr_h, nwp, n2p, nb1, nb2, out);
    }
}

// Round 20
// 561.873 us; speedup vs baseline: 1.2973x; 1.2973x over previous
//
#include <hip/hip_runtime.h>
#include <hip/hip_fp16.h>
#include <math.h>

typedef unsigned int uint;
typedef __fp16 half2_t __attribute__((ext_vector_type(2)));
typedef _Float16 v8h __attribute__((ext_vector_type(8)));
typedef _Float16 v4h __attribute__((ext_vector_type(4)));
typedef float f32v4 __attribute__((ext_vector_type(4)));

#define NUM_P 3
#define NUM_N 50000
#define NUM_C 5
#define NUM_E 150000
#define CF 340
#define NB32 1563               // ceil(N/32)
#define TE 128                  // edges per edge block
#define EB2 1172                // ceil(E/TE)
#define TN 128                  // nodes per node block
#define NB128 391               // ceil(N/TN)
#define SROW 129                // odd LDS row stride (fallback node kernel)
#define NSB 196                 // scan blocks per plane (ceil(N/256))
#define NSBP 50176              // NSB*256
#define NST 44                  // node_mfma LDS row stride (uints)

// ---- sizes (uint units) ----
#define AH_T   ((size_t)NUM_P * NUM_N * 170)     // aggr_h / xh / xn: 25,500,000
#define NW1_T  (NUM_P * NUM_C * 68 * 64)         // 65,280
#define NW2_T  (NUM_P * NUM_C * 32 * 64)         // 30,720
#define LG_T   ((size_t)NUM_P * NUM_C * NUM_E)   // 2,250,000
#define EWB_T  (NUM_P * NUM_C * 2 * 4 * 640)     // 76,800 mfma-frag weights

__device__ __forceinline__ float fast_tanh(float x) {
    float a = __expf(2.0f * x);
    float t = __builtin_amdgcn_rcpf(a + 1.0f);
    return fmaf(-2.0f, t, 1.0f);
}

__device__ __forceinline__ float dot2f(half2_t a, half2_t b, float c) {
#if __has_builtin(__builtin_amdgcn_fdot2)
    return __builtin_amdgcn_fdot2(a, b, c, false);
#else
    return fmaf((float)a[0], (float)b[0], fmaf((float)a[1], (float)b[1], c));
#endif
}

__device__ __forceinline__ half2_t bc(uint u) { return __builtin_bit_cast(half2_t, u); }

__device__ __forceinline__ uint pk2(float a, float b) {
    half2_t h = __builtin_amdgcn_cvt_pkrtz(a, b);
    return __builtin_bit_cast(uint, h);
}

__device__ __forceinline__ v8h mk8(uint a, uint b, uint c, uint d) {
    uint4 u; u.x = a; u.y = b; u.z = c; u.w = d;
    return __builtin_bit_cast(v8h, u);
}

// ---------------------------------------------------------------------------
// Transpose x -> xh [P][C][N][34] (class-major) + xn [P][N][170], f16 pairs.
// ---------------------------------------------------------------------------
__global__ __launch_bounds__(256) void convert_x_kernel(
    const float4* __restrict__ x4, uint* __restrict__ xh,
    uint* __restrict__ xn, int write_xn)
{
    __shared__ uint lds[32 * 170];
    const int nb = blockIdx.x % NB32;
    const int p  = blockIdx.x / NB32;
    const int n0 = nb * 32;
    const int nvalid = (n0 + 32 <= NUM_N) ? 32 : (NUM_N - n0);
    const int t = threadIdx.x;

    const float4* src = x4 + ((size_t)p * NUM_N + n0) * 85;
    const int nf4 = nvalid * 85;
    #pragma unroll
    for (int it = 0; it < 11; ++it) {
        const int i = t + it * 256;
        if (i < nf4) {
            const float4 v = src[i];
            lds[2 * i]     = pk2(v.x, v.y);
            lds[2 * i + 1] = pk2(v.z, v.w);
        }
    }
    __syncthreads();

    const int nq = nvalid * 34;
    #pragma unroll 1
    for (int c = 0; c < NUM_C; ++c) {
        uint* dst = xh + ((size_t)(p * NUM_C + c) * NUM_N + n0) * 34;
        #pragma unroll
        for (int it = 0; it < 5; ++it) {
            const int i = t + it * 256;
            if (i < nq) {
                const int nl = i / 34, j = i - nl * 34;
                dst[i] = lds[nl * 170 + c * 34 + j];
            }
        }
    }

    if (write_xn) {
        uint* dstn = xn + ((size_t)p * NUM_N + n0) * 170;
        const int tot = nvalid * 170;
        #pragma unroll
        for (int it = 0; it < 22; ++it) {
            const int i = t + it * 256;
            if (i < tot) dstn[i] = lds[i];
        }
    }
}

// pair-major weight pack: out[t*64+o] = (w[2t][o], w[2t+1][o])
__global__ __launch_bounds__(256) void pack_pairs_kernel(
    const float* __restrict__ in, uint* __restrict__ outp, int total)
{
    int i = blockIdx.x * 256 + threadIdx.x;
    if (i >= total) return;
    int t = i >> 6, o = i & 63;
    outp[i] = pk2(in[t * 128 + o], in[t * 128 + 64 + o]);
}

// ---------------------------------------------------------------------------
// Edge-weight pack into MFMA B-fragment linear order.
// ---------------------------------------------------------------------------
__global__ __launch_bounds__(256) void pack_edge_mfma_kernel(
    const float* __restrict__ ew1, uint* __restrict__ ewb)
{
    int i = blockIdx.x * 256 + threadIdx.x;
    if (i >= EWB_T) return;
    int g    = i / 5120;
    int rem  = i - g * 5120;
    int s    = rem / 2560;
    int rem2 = rem - s * 2560;
    int nt   = rem2 / 640;
    int u    = rem2 - nt * 640;

    int f0, o; bool valid;
    if (u < 512) {
        int kt = u >> 8, uu = u & 255;
        int lane = uu >> 2, pp = uu & 3;
        f0 = kt * 32 + (lane >> 4) * 8 + 2 * pp;
        o  = nt * 16 + (lane & 15);
        valid = true;
    } else {
        int uu = u - 512;
        int lane = uu >> 1, pp = uu & 1;
        f0 = 64 + (lane >> 4) * 4 + 2 * pp;
        o  = nt * 16 + (lane & 15);
        valid = ((lane >> 4) == 0);
    }
    float w0 = 0.f, w1 = 0.f;
    if (valid) {
        int f = s * 68 + f0;
        w0 = ew1[((size_t)g * 136 + f) * 64 + o];
        w1 = ew1[((size_t)g * 136 + f + 1) * 64 + o];
    }
    ewb[i] = pk2(w0, w1);
}

// ---------------------------------------------------------------------------
// Edge MLP via MFMA (round-16 verified configuration: 128 threads / 2 waves,
// stride 40, serial two-side staging, LDS-transpose epilogue).
// ---------------------------------------------------------------------------
__global__ __launch_bounds__(128) void edge_mfma_kernel(
    const uint*  __restrict__ xh,       // [P*C][N][34]
    const int*   __restrict__ ei,       // [P][2][E]      (ei mode)
    const int*   __restrict__ csr_src,  // [P][E]         (csr mode)
    const int*   __restrict__ csr_dst,  // [P][E]         (csr mode)
    const uint*  __restrict__ ewb,
    const float* __restrict__ eb1,
    const float* __restrict__ ew2,
    const float* __restrict__ eb2,
    float*       __restrict__ logits,   // [g][E] indexed by pos (csr) or e (ei)
    int use_csr)
{
    __shared__ uint smem[TE * 40];
    __shared__ int  ids[2][TE];

    const int g    = blockIdx.x / EB2;
    const int blk  = blockIdx.x - g * EB2;
    const int p    = g / NUM_C;
    const int e0   = blk * TE;
    const int t    = threadIdx.x;
    const int lane = t & 63;
    const int wv   = t >> 6;
    const int col  = lane & 15;
    const int G    = lane >> 4;

    {
        const int e  = e0 + t;
        const int ec = (e < NUM_E) ? e : (NUM_E - 1);
        if (use_csr) {
            ids[0][t] = csr_src[(size_t)p * NUM_E + ec];   // src (x_j)
            ids[1][t] = csr_dst[(size_t)p * NUM_E + ec];   // dst (x_i)
        } else {
            ids[0][t] = ei[(p * 2 + 0) * NUM_E + ec];
            ids[1][t] = ei[(p * 2 + 1) * NUM_E + ec];
        }
    }
    {
        const uint2 z = make_uint2(0u, 0u);
        *(uint2*)&smem[t * 40 + 34] = z;
        *(uint2*)&smem[t * 40 + 36] = z;
        *(uint2*)&smem[t * 40 + 38] = z;
    }

    const uint* slice = xh + (size_t)g * NUM_N * 34;

    float b1v[4], w2v[4];
    #pragma unroll
    for (int nt = 0; nt < 4; ++nt) {
        b1v[nt] = eb1[g * 64 + nt * 16 + col];
        w2v[nt] = ew2[g * 64 + nt * 16 + col];
    }

    f32v4 acc[4][4];
    #pragma unroll
    for (int m = 0; m < 4; ++m)
        #pragma unroll
        for (int nt = 0; nt < 4; ++nt) {
            f32v4 a = {b1v[nt], b1v[nt], b1v[nt], b1v[nt]};
            acc[m][nt] = a;
        }
    __syncthreads();

    #pragma unroll 1
    for (int side = 0; side < 2; ++side) {
        const int* idr = ids[1 - side];            // side0 = x_i(dst), side1 = x_j(src)
        #pragma unroll
        for (int k = 0; k < 17; ++k) {
            const int i2 = t + TE * k;
            const int e  = i2 / 17, j2 = i2 - e * 17;
            const uint2 v = *(const uint2*)(slice + (size_t)idr[e] * 34 + 2 * j2);
            *(uint2*)&smem[e * 40 + 2 * j2] = v;
        }
        __syncthreads();

        const uint* wb = ewb + (size_t)((g * 2 + side) * 4) * 640;
        v8h B0[4], B1[4]; v4h B2[4];
        #pragma unroll
        for (int nt = 0; nt < 4; ++nt) {
            const uint* fb = wb + nt * 640;
            B0[nt] = __builtin_bit_cast(v8h, *(const uint4*)(fb + lane * 4));
            B1[nt] = __builtin_bit_cast(v8h, *(const uint4*)(fb + 256 + lane * 4));
            B2[nt] = __builtin_bit_cast(v4h, *(const uint2*)(fb + 512 + lane * 2));
        }

        #pragma unroll
        for (int m = 0; m < 4; ++m) {
            const uint* rp = &smem[(wv * 64 + m * 16 + col) * 40];
            const v8h A0 = __builtin_bit_cast(v8h, *(const uint4*)(rp + G * 4));
            const v8h A1 = __builtin_bit_cast(v8h, *(const uint4*)(rp + 16 + G * 4));
            const v4h A2 = __builtin_bit_cast(v4h, *(const uint2*)(rp + 32 + G * 2));
            #pragma unroll
            for (int nt = 0; nt < 4; ++nt) {
                acc[m][nt] = __builtin_amdgcn_mfma_f32_16x16x32_f16(A0, B0[nt], acc[m][nt], 0, 0, 0);
                acc[m][nt] = __builtin_amdgcn_mfma_f32_16x16x32_f16(A1, B1[nt], acc[m][nt], 0, 0, 0);
                acc[m][nt] = __builtin_amdgcn_mfma_f32_16x16x16f16(A2, B2[nt], acc[m][nt], 0, 0, 0);
            }
        }
        __syncthreads();
    }

    float* elds = (float*)smem;
    #pragma unroll
    for (int m = 0; m < 4; ++m) {
        #pragma unroll
        for (int r = 0; r < 4; ++r) {
            float part = 0.f;
            #pragma unroll
            for (int nt = 0; nt < 4; ++nt)
                part = fmaf(w2v[nt], fast_tanh(acc[m][nt][r]), part);
            elds[(wv * 64 + m * 16 + G * 4 + r) * 20 + col] = part;
        }
    }
    const float4 s0 = *(const float4*)&elds[t * 20 + 0];
    const float4 s1 = *(const float4*)&elds[t * 20 + 4];
    const float4 s2 = *(const float4*)&elds[t * 20 + 8];
    const float4 s3 = *(const float4*)&elds[t * 20 + 12];
    float lg = ((s0.x + s0.y) + (s0.z + s0.w)) + ((s1.x + s1.y) + (s1.z + s1.w))
             + ((s2.x + s2.y) + (s2.z + s2.w)) + ((s3.x + s3.y) + (s3.z + s3.w))
             + eb2[g];
    if (e0 + t < NUM_E) logits[(size_t)g * NUM_E + e0 + t] = lg;
}

// ---------------------------------------------------------------------------
// Per-edge softmax: thread = (p,pos) -> wbuf[P][C][E].
// ---------------------------------------------------------------------------
__global__ __launch_bounds__(256) void softmax_kernel(
    const float* __restrict__ logits, float* __restrict__ wbuf)
{
    const int i = blockIdx.x * 256 + threadIdx.x;
    if (i >= NUM_P * NUM_E) return;
    const int p = i / NUM_E, e = i - p * NUM_E;
    const size_t base = (size_t)p * NUM_C * NUM_E + e;
    float l[NUM_C];
    #pragma unroll
    for (int c = 0; c < NUM_C; ++c) l[c] = logits[base + (size_t)c * NUM_E];
    float m = l[0];
    #pragma unroll
    for (int c = 1; c < NUM_C; ++c) m = fmaxf(m, l[c]);
    float s = 0.f;
    #pragma unroll
    for (int c = 0; c < NUM_C; ++c) { l[c] = __expf(l[c] - m); s += l[c]; }
    const float inv = __builtin_amdgcn_rcpf(s);
    #pragma unroll
    for (int c = 0; c < NUM_C; ++c) wbuf[base + (size_t)c * NUM_E] = l[c] * inv;
}

// ---------------------------------------------------------------------------
// CSR build.
// ---------------------------------------------------------------------------
__global__ __launch_bounds__(256) void deg_kernel(
    const int* __restrict__ ei, int* __restrict__ deg)
{
    const int i = blockIdx.x * 256 + threadIdx.x;
    if (i >= NUM_P * NUM_E) return;
    const int p = i / NUM_E, e = i - p * NUM_E;
    const int dst = ei[(p * 2 + 1) * NUM_E + e];
    atomicAdd(&deg[p * NUM_N + dst], 1);
}

__global__ __launch_bounds__(256) void scan_block_kernel(
    const int* __restrict__ deg, int* __restrict__ intra, int* __restrict__ bsum)
{
    __shared__ int s[256];
    const int blk = blockIdx.x % NSB;
    const int p   = blockIdx.x / NSB;
    const int t   = threadIdx.x;
    const int n   = blk * 256 + t;
    const int d   = (n < NUM_N) ? deg[p * NUM_N + n] : 0;
    s[t] = d;
    __syncthreads();
    #pragma unroll
    for (int o = 1; o < 256; o <<= 1) {
        int v = (t >= o) ? s[t - o] : 0;
        __syncthreads();
        s[t] += v;
        __syncthreads();
    }
    if (n < NUM_N) intra[p * NSBP + n] = s[t] - d;
    if (t == 255) bsum[p * NSB + blk] = s[255];
}

__global__ __launch_bounds__(256) void scan_seg_kernel(
    const int* __restrict__ bsum, int* __restrict__ segoff)
{
    __shared__ int s[256];
    const int t = threadIdx.x;
    #pragma unroll 1
    for (int p = 0; p < NUM_P; ++p) {
        const int b = (t < NSB) ? bsum[p * NSB + t] : 0;
        s[t] = b;
        __syncthreads();
        #pragma unroll
        for (int o = 1; o < 256; o <<= 1) {
            int v = (t >= o) ? s[t - o] : 0;
            __syncthreads();
            s[t] += v;
            __syncthreads();
        }
        if (t < NSB) segoff[p * NSB + t] = s[t] - b;
        __syncthreads();
    }
}

__global__ __launch_bounds__(256) void fill_kernel(
    const int* __restrict__ ei, int* __restrict__ cursor,
    const int* __restrict__ intra, const int* __restrict__ segoff,
    int* __restrict__ csr_src, int* __restrict__ csr_dst)
{
    const int i = blockIdx.x * 256 + threadIdx.x;
    if (i >= NUM_P * NUM_E) return;
    const int p = i / NUM_E, e = i - p * NUM_E;
    const int src = ei[(p * 2 + 0) * NUM_E + e];
    const int dst = ei[(p * 2 + 1) * NUM_E + e];
    const int slot = atomicAdd(&cursor[p * NUM_N + dst], 1);
    const int pos  = segoff[p * NSB + (dst >> 8)] + intra[p * NSBP + dst] + slot;
    csr_src[(size_t)p * NUM_E + pos] = src;
    csr_dst[(size_t)p * NUM_E + pos] = dst;
}

// ---------------------------------------------------------------------------
// Gather: wave per (p, dst-node); gate weights read SEQUENTIALLY by CSR pos.
// ---------------------------------------------------------------------------
__global__ __launch_bounds__(256) void gather_kernel(
    const uint*  __restrict__ xn,
    const float* __restrict__ wbuf,    // [P][C][E], indexed by pos
    const int*   __restrict__ csr_src,
    const int*   __restrict__ deg,
    const int*   __restrict__ intra,
    const int*   __restrict__ segoff,
    uint*        __restrict__ aggr)
{
    const int wslot = threadIdx.x >> 6;
    const int lane  = threadIdx.x & 63;
    const int gw = blockIdx.x * 4 + wslot;
    const int p  = gw / NUM_N;
    const int n  = gw - p * NUM_N;

    const int dg   = deg[p * NUM_N + n];
    const int off0 = segoff[p * NSB + (n >> 8)] + intra[p * NSBP + n];

    const int q1 = lane + 64, q2 = lane + 128;
    const int c0 = lane / 34;
    const int c1 = q1 / 34;
    const int c2 = q2 / 34;

    float a0 = 0.f, a1 = 0.f, a2 = 0.f, a3 = 0.f, a4 = 0.f, a5 = 0.f;

    #pragma unroll 1
    for (int d = 0; d < dg; ++d) {
        const int pos = off0 + d;
        const int src = csr_src[(size_t)p * NUM_E + pos];

        const float wa = wbuf[(size_t)(p * NUM_C + c0) * NUM_E + pos];
        const float wb = wbuf[(size_t)(p * NUM_C + c1) * NUM_E + pos];
        const float wc = (lane < 42) ? wbuf[(size_t)(p * NUM_C + c2) * NUM_E + pos] : 0.f;

        const uint* row = xn + (size_t)(p * NUM_N + src) * 170;
        const uint u0 = row[lane];
        const uint u1 = row[q1];
        const uint u2 = (lane < 42) ? row[q2] : 0u;
        const half2_t h0 = bc(u0), h1 = bc(u1), h2 = bc(u2);
        a0 = fmaf(wa, (float)h0[0], a0);
        a1 = fmaf(wa, (float)h0[1], a1);
        a2 = fmaf(wb, (float)h1[0], a2);
        a3 = fmaf(wb, (float)h1[1], a3);
        a4 = fmaf(wc, (float)h2[0], a4);
        a5 = fmaf(wc, (float)h2[1], a5);
    }

    const int i0 = lane - c0 * 34;
    const int i1 = q1 - c1 * 34;
    const int i2 = q2 - c2 * 34;
    aggr[((size_t)(p * NUM_C + c0) * NUM_N + n) * 34 + i0] = pk2(a0, a1);
    aggr[((size_t)(p * NUM_C + c1) * NUM_N + n) * 34 + i1] = pk2(a2, a3);
    if (lane < 42)
        aggr[((size_t)(p * NUM_C + c2) * NUM_N + n) * 34 + i2] = pk2(a4, a5);
}

// ---------------------------------------------------------------------------
// Fallback scatter (only if !fits). logits indexed by e (ei order).
// ---------------------------------------------------------------------------
__global__ __launch_bounds__(256) void edge_scatter_kernel(
    const uint*  __restrict__ xh,
    const int*   __restrict__ ei,
    const float* __restrict__ logits,
    uint*        __restrict__ aggr)
{
    const int wslot = threadIdx.x >> 6;
    const int lane  = threadIdx.x & 63;
    const int gw    = blockIdx.x * 4 + wslot;
    const int p     = gw / NUM_E;
    const int e     = gw - p * NUM_E;

    const int src = ei[(p * 2 + 0) * NUM_E + e];
    const int dst = ei[(p * 2 + 1) * NUM_E + e];

    float l[NUM_C];
    #pragma unroll
    for (int c = 0; c < NUM_C; ++c)
        l[c] = logits[(size_t)(p * NUM_C + c) * NUM_E + e];
    float m = l[0];
    #pragma unroll
    for (int c = 1; c < NUM_C; ++c) m = fmaxf(m, l[c]);
    float s = 0.f;
    #pragma unroll
    for (int c = 0; c < NUM_C; ++c) { l[c] = __expf(l[c] - m); s += l[c]; }
    const float inv = __builtin_amdgcn_rcpf(s);
    const float wt0 = l[0] * inv, wt1 = l[1] * inv, wt2 = l[2] * inv,
                wt3 = l[3] * inv, wt4 = l[4] * inv;

    #pragma unroll
    for (int k = 0; k < 3; ++k) {
        const int q = lane + 64 * k;
        if (q < 170) {
            const int c   = q / 34;
            const int idx = q - c * 34;
            const float wv = (c == 0) ? wt0 : (c == 1) ? wt1 : (c == 2) ? wt2
                           : (c == 3) ? wt3 : wt4;
            const uint xv = xh[((size_t)(p * NUM_C + c) * NUM_N + src) * 34 + idx];
            half2_t mv = __builtin_amdgcn_cvt_pkrtz(wv, wv) * bc(xv);
            uint* ap = aggr + ((size_t)(p * NUM_C + c) * NUM_N + dst) * 34 + idx;
            unsafeAtomicAdd((__half2*)ap, __builtin_bit_cast(__half2, mv));
        }
    }
}

// ---------------------------------------------------------------------------
// Node MLP via MFMA v2.
// ---------------------------------------------------------------------------
__global__ __launch_bounds__(256) void node_mfma_kernel(
    const uint*  __restrict__ xh,
    const uint*  __restrict__ aggr,
    const uint*  __restrict__ nwp,
    const uint*  __restrict__ n2p,
    const float* __restrict__ nb1,
    const float* __restrict__ nb2,
    float*       __restrict__ out)
{
    __shared__ uint smem[TN * NST];

    const int g    = blockIdx.x / NB128;
    const int blk  = blockIdx.x - g * NB128;
    const int p    = g / NUM_C;
    const int c    = g - p * NUM_C;
    const int n0   = blk * TN;
    const int t    = threadIdx.x;
    const int lane = t & 63;
    const int wv   = t >> 6;
    const int col  = lane & 15;
    const int G    = lane >> 4;
    const int nvalid = (n0 + TN <= NUM_N) ? TN : (NUM_N - n0);
    const int lim2   = nvalid * 17;

    if (t < TN) {
        const uint2 z = make_uint2(0u, 0u);
        *(uint2*)&smem[t * NST + 34] = z;
        *(uint2*)&smem[t * NST + 36] = z;
        *(uint2*)&smem[t * NST + 38] = z;
    }

    const uint* wgp = nwp + (size_t)g * 68 * 64;

    float b1v[4];
    #pragma unroll
    for (int nt = 0; nt < 4; ++nt) b1v[nt] = nb1[g * 64 + nt * 16 + col];

    f32v4 acc[2][4];
    #pragma unroll
    for (int mt = 0; mt < 2; ++mt)
        #pragma unroll
        for (int nt = 0; nt < 4; ++nt) {
            f32v4 a = {b1v[nt], b1v[nt], b1v[nt], b1v[nt]};
            acc[mt][nt] = a;
        }

    #pragma unroll 1
    for (int side = 0; side < 2; ++side) {
        const uint* srcp = (side == 0 ? xh : aggr) + ((size_t)g * NUM_N + n0) * 34;
        #pragma unroll
        for (int k = 0; k < 9; ++k) {
            const int i2 = t + 256 * k;
            if (i2 < TN * 17) {
                const int i2c = (i2 < lim2) ? i2 : (lim2 - 1);
                const uint2 v = *(const uint2*)(srcp + 2 * i2c);
                const int nl = i2 / 17, j2 = i2 - nl * 17;
                *(uint2*)&smem[nl * NST + 2 * j2] = v;
            }
        }
        __syncthreads();

        v8h B0[4], B1[4]; v4h B2[4];
        #pragma unroll
        for (int nt = 0; nt < 4; ++nt) {
            const int oc = nt * 16 + col;
            const int r0 = side * 34 + G * 4;
            B0[nt] = mk8(wgp[(r0 + 0) * 64 + oc], wgp[(r0 + 1) * 64 + oc],
                         wgp[(r0 + 2) * 64 + oc], wgp[(r0 + 3) * 64 + oc]);
            const int r1 = r0 + 16;
            B1[nt] = mk8(wgp[(r1 + 0) * 64 + oc], wgp[(r1 + 1) * 64 + oc],
                         wgp[(r1 + 2) * 64 + oc], wgp[(r1 + 3) * 64 + oc]);
            uint b2a = (G == 0) ? wgp[(side * 34 + 32) * 64 + oc] : 0u;
            uint b2b = (G == 0) ? wgp[(side * 34 + 33) * 64 + oc] : 0u;
            uint2 u2; u2.x = b2a; u2.y = b2b;
            B2[nt] = __builtin_bit_cast(v4h, u2);
        }

        #pragma unroll
        for (int mt = 0; mt < 2; ++mt) {
            const uint* rp = &smem[(wv * 32 + mt * 16 + col) * NST];
            const v8h A0 = __builtin_bit_cast(v8h, *(const uint4*)(rp + G * 4));
            const v8h A1 = __builtin_bit_cast(v8h, *(const uint4*)(rp + 16 + G * 4));
            const v4h A2 = __builtin_bit_cast(v4h, *(const uint2*)(rp + 32 + G * 2));
            #pragma unroll
            for (int nt = 0; nt < 4; ++nt) {
                acc[mt][nt] = __builtin_amdgcn_mfma_f32_16x16x32_f16(A0, B0[nt], acc[mt][nt], 0, 0, 0);
                acc[mt][nt] = __builtin_amdgcn_mfma_f32_16x16x32_f16(A1, B1[nt], acc[mt][nt], 0, 0, 0);
                acc[mt][nt] = __builtin_amdgcn_mfma_f32_16x16x16f16(A2, B2[nt], acc[mt][nt], 0, 0, 0);
            }
        }
        __syncthreads();
    }

    _Float16* hl = (_Float16*)smem;
    #pragma unroll
    for (int mt = 0; mt < 2; ++mt)
        #pragma unroll
        for (int nt = 0; nt < 4; ++nt)
            #pragma unroll
            for (int r = 0; r < 4; ++r)
                hl[(wv * 32 + mt * 16 + G * 4 + r) * 72 + nt * 16 + col] =
                    (_Float16)fast_tanh(acc[mt][nt][r]);

    const uint* w2p = n2p + (size_t)g * 32 * 64;
    float b2v[4];
    #pragma unroll
    for (int nt = 0; nt < 4; ++nt) b2v[nt] = nb2[g * 64 + nt * 16 + col];

    f32v4 acc2[2][4];
    #pragma unroll
    for (int mt = 0; mt < 2; ++mt)
        #pragma unroll
        for (int nt = 0; nt < 4; ++nt) {
            f32v4 a = {b2v[nt], b2v[nt], b2v[nt], b2v[nt]};
            acc2[mt][nt] = a;
        }

    v8h C0[4], C1[4];
    #pragma unroll
    for (int nt = 0; nt < 4; ++nt) {
        const int oc = nt * 16 + col;
        C0[nt] = mk8(w2p[(G * 4 + 0) * 64 + oc], w2p[(G * 4 + 1) * 64 + oc],
                     w2p[(G * 4 + 2) * 64 + oc], w2p[(G * 4 + 3) * 64 + oc]);
        C1[nt] = mk8(w2p[(16 + G * 4 + 0) * 64 + oc], w2p[(16 + G * 4 + 1) * 64 + oc],
                     w2p[(16 + G * 4 + 2) * 64 + oc], w2p[(16 + G * 4 + 3) * 64 + oc]);
    }

    #pragma unroll
    for (int mt = 0; mt < 2; ++mt) {
        const uint* rp = &smem[(wv * 32 + mt * 16 + col) * 36];
        const v8h A0 = __builtin_bit_cast(v8h, *(const uint4*)(rp + G * 4));
        const v8h A1 = __builtin_bit_cast(v8h, *(const uint4*)(rp + 16 + G * 4));
        #pragma unroll
        for (int nt = 0; nt < 4; ++nt) {
            acc2[mt][nt] = __builtin_amdgcn_mfma_f32_16x16x32_f16(A0, C0[nt], acc2[mt][nt], 0, 0, 0);
            acc2[mt][nt] = __builtin_amdgcn_mfma_f32_16x16x32_f16(A1, C1[nt], acc2[mt][nt], 0, 0, 0);
        }
    }
    __syncthreads();

    float* elds = (float*)smem;
    #pragma unroll
    for (int pass = 0; pass < 2; ++pass) {
        #pragma unroll
        for (int mt = 0; mt < 2; ++mt)
            #pragma unroll
            for (int r = 0; r < 4; ++r) {
                const int row = wv * 32 + mt * 16 + G * 4 + r;
                elds[row * NST + col]      = fast_tanh(acc2[mt][2 * pass][r]);
                elds[row * NST + 16 + col] = fast_tanh(acc2[mt][2 * pass + 1][r]);
            }
        const int row = wv * 32 + (lane >> 1);
        if (row < nvalid) {
            float* op = out + ((size_t)(p * NUM_N + n0 + row) * NUM_C + c) * 64
                      + pass * 32 + (lane & 1) * 16;
            const float* ep = &elds[row * NST + (lane & 1) * 16];
            #pragma unroll
            for (int q = 0; q < 4; ++q)
                *(float4*)(op + q * 4) = *(const float4*)(ep + q * 4);
        }
        if (pass == 0) __syncthreads();
    }
}

// ---------------------------------------------------------------------------
// Fallback node kernel (dot2, fp32 x path) — used only when !fits.
// ---------------------------------------------------------------------------
__device__ __forceinline__ void dot_side(const uint* __restrict__ xp,
                                         const uint* __restrict__ wp,
                                         float acc[64])
{
    uint2 cur = *(const uint2*)(xp);
    #pragma unroll 1
    for (int j = 0; j < 17; ++j) {
        const int jn = (j < 16) ? (j + 1) : 16;
        const uint2 nxt = *(const uint2*)(xp + jn * 2);
        const half2_t a0 = bc(cur.x);
        const half2_t a1 = bc(cur.y);
        const uint* w0 = wp + (2 * j) * 64;
        #pragma unroll
        for (int o = 0; o < 64; ++o)
            acc[o] = dot2f(a0, bc(w0[o]), acc[o]);
        const uint* w1 = w0 + 64;
        #pragma unroll
        for (int o = 0; o < 64; ++o)
            acc[o] = dot2f(a1, bc(w1[o]), acc[o]);
        cur = nxt;
    }
}

__global__ __launch_bounds__(128) void node_kernel(
    const float* __restrict__ x,
    const uint*  __restrict__ aggr,
    const uint*  __restrict__ nwp,
    const uint*  __restrict__ n2p,
    const float* __restrict__ nb1,
    const float* __restrict__ nb2,
    float*       __restrict__ out)
{
    __shared__ uint buf[34][SROW];

    const int g   = blockIdx.x / NB128;
    const int blk = blockIdx.x - g * NB128;
    const int p   = g / NUM_C;
    const int c   = g - p * NUM_C;
    const int n0  = blk * TN;
    const int t   = threadIdx.x;
    const int nvalid = (n0 + TN <= NUM_N) ? TN : (NUM_N - n0);
    const int lim2 = nvalid * 17;

    float acc[64];
    const float* b1 = nb1 + g * 64;
    #pragma unroll
    for (int o4 = 0; o4 < 64; o4 += 4) {
        const float4 bv = *(const float4*)(b1 + o4);
        acc[o4] = bv.x; acc[o4 + 1] = bv.y; acc[o4 + 2] = bv.z; acc[o4 + 3] = bv.w;
    }
    const uint* wg = nwp + (size_t)g * 68 * 64;

    #pragma unroll
    for (int k = 0; k < 34; ++k) {
        const int i  = t + TN * k;
        const int nl = i / 34, j = i - nl * 34;
        const int nn = (nl < nvalid) ? (n0 + nl) : n0;
        const float2 v = *(const float2*)(x + ((size_t)p * NUM_N + nn) * CF
                                          + c * 68 + 2 * j);
        buf[j][nl] = pk2(v.x, v.y);
    }
    __syncthreads();
    #pragma unroll 1
    for (int j = 0; j < 34; ++j) {
        const half2_t a = bc(buf[j][t]);
        const uint* w = wg + j * 64;
        #pragma unroll
        for (int o = 0; o < 64; ++o) acc[o] = dot2f(a, bc(w[o]), acc[o]);
    }
    __syncthreads();

    {
        const uint* srcp = aggr + ((size_t)g * NUM_N + n0) * 34;
        #pragma unroll
        for (int k = 0; k < 17; ++k) {
            const int i2  = t + TN * k;
            const int i2c = (i2 < lim2) ? i2 : (lim2 - 1);
            const uint2 v = *(const uint2*)(srcp + 2 * i2c);
            const int nl = i2 / 17, j2 = i2 - nl * 17;
            buf[2 * j2][nl]     = v.x;
            buf[2 * j2 + 1][nl] = v.y;
        }
    }
    __syncthreads();
    #pragma unroll 1
    for (int j = 0; j < 34; ++j) {
        const half2_t a = bc(buf[j][t]);
        const uint* w = wg + (34 + j) * 64;
        #pragma unroll
        for (int o = 0; o < 64; ++o) acc[o] = dot2f(a, bc(w[o]), acc[o]);
    }

    uint h2p[32];
    #pragma unroll
    for (int f2 = 0; f2 < 32; ++f2)
        h2p[f2] = pk2(fast_tanh(acc[2 * f2]), fast_tanh(acc[2 * f2 + 1]));

    const float* b2 = nb2 + g * 64;
    float acc2[64];
    #pragma unroll
    for (int o4 = 0; o4 < 64; o4 += 4) {
        const float4 bv = *(const float4*)(b2 + o4);
        acc2[o4] = bv.x; acc2[o4 + 1] = bv.y; acc2[o4 + 2] = bv.z; acc2[o4 + 3] = bv.w;
    }
    const uint* w2g = n2p + (size_t)g * 32 * 64;
    #pragma unroll
    for (int f2 = 0; f2 < 32; ++f2) {
        const half2_t hv = bc(h2p[f2]);
        const uint* wr = w2g + f2 * 64;
        #pragma unroll
        for (int o = 0; o < 64; ++o)
            acc2[o] = dot2f(hv, bc(wr[o]), acc2[o]);
    }

    if (t < nvalid) {
        float* op = out + ((size_t)(p * NUM_N + n0 + t) * NUM_C + c) * 64;
        #pragma unroll
        for (int o4 = 0; o4 < 64; o4 += 4) {
            float4 ov;
            ov.x = fast_tanh(acc2[o4 + 0]);
            ov.y = fast_tanh(acc2[o4 + 1]);
            ov.z = fast_tanh(acc2[o4 + 2]);
            ov.w = fast_tanh(acc2[o4 + 3]);
            *(float4*)(op + o4) = ov;
        }
    }
}

extern "C" void kernel_launch(void* const* d_in, const int* in_sizes, int n_in,
                              void* d_out, int out_size, void* d_ws, size_t ws_size,
                              hipStream_t stream)
{
    (void)in_sizes; (void)n_in; (void)out_size;

    const float* x   = (const float*)d_in[0];
    const int*   ei  = (const int*)  d_in[1];
    const float* ew1 = (const float*)d_in[2];
    const float* eb1 = (const float*)d_in[3];
    const float* ew2 = (const float*)d_in[4];
    const float* eb2 = (const float*)d_in[5];
    const float* nw1 = (const float*)d_in[6];
    const float* nb1 = (const float*)d_in[7];
    const float* nw2 = (const float*)d_in[8];
    const float* nb2 = (const float*)d_in[9];
    float*       out = (float*)d_out;

    // ws (uints): [aggr_h | nwp | n2p | xh]
    uint* ws     = (uint*)d_ws;
    uint* aggr_h = ws;
    uint* nwp    = ws + AH_T;
    uint* n2p    = nwp + NW1_T;
    const size_t o_xh = AH_T + NW1_T + NW2_T;
    const bool fits = ws_size >= (o_xh + AH_T) * sizeof(uint);
    uint*  xh     = fits ? (ws + o_xh) : (uint*)d_out;
    uint*  xn     = (uint*)d_out;
    float* logits = (float*)((uint*)d_out + AH_T);
    uint*  ewb    = (uint*)d_out + AH_T + LG_T;

    int* ibase   = (int*)(ewb + EWB_T);
    int* deg     = ibase;
    int* cursor  = ibase + NUM_P * NUM_N;
    int* intra   = cursor + NUM_P * NUM_N;
    int* bsum    = intra + NUM_P * NSBP;
    int* segoff  = bsum + NUM_P * NSB;
    int* csr_src = segoff + NUM_P * NSB;
    int* csr_dst = csr_src + NUM_P * NUM_E;
    float* wbuf  = (float*)(csr_dst + NUM_P * NUM_E);   // [P][C][E]

    convert_x_kernel<<<NUM_P * NB32, 256, 0, stream>>>(
        (const float4*)x, xh, xn, fits ? 1 : 0);
    pack_edge_mfma_kernel<<<(EWB_T + 255) / 256, 256, 0, stream>>>(ew1, ewb);
    pack_pairs_kernel<<<(NW1_T + 255) / 256, 256, 0, stream>>>(nw1, nwp, NW1_T);
    pack_pairs_kernel<<<(NW2_T + 255) / 256, 256, 0, stream>>>(nw2, n2p, NW2_T);

    if (fits) {
        (void)hipMemsetAsync(ibase, 0, (size_t)2 * NUM_P * NUM_N * sizeof(int), stream);
        const int egrid = (NUM_P * NUM_E + 255) / 256;
        deg_kernel<<<egrid, 256, 0, stream>>>(ei, deg);
        scan_block_kernel<<<NUM_P * NSB, 256, 0, stream>>>(deg, intra, bsum);
        scan_seg_kernel<<<1, 256, 0, stream>>>(bsum, segoff);
        fill_kernel<<<egrid, 256, 0, stream>>>(ei, cursor, intra, segoff,
                                               csr_src, csr_dst);

        edge_mfma_kernel<<<NUM_P * NUM_C * EB2, 128, 0, stream>>>(
            xh, ei, csr_src, csr_dst, ewb, eb1, ew2, eb2, logits, 1);
        softmax_kernel<<<egrid, 256, 0, stream>>>(logits, wbuf);
        gather_kernel<<<(NUM_P * NUM_N) / 4, 256, 0, stream>>>(
            xn, wbuf, csr_src, deg, intra, segoff, aggr_h);
        node_mfma_kernel<<<NUM_P * NUM_C * NB128, 256, 0, stream>>>(
            xh, aggr_h, nwp, n2p, nb1, nb2, out);
    } else {
        edge_mfma_kernel<<<NUM_P * NUM_C * EB2, 128, 0, stream>>>(
            xh, ei, (const int*)ei, (const int*)ei, ewb, eb1, ew2, eb2, logits, 0);
        (void)hipMemsetAsync(aggr_h, 0, AH_T * sizeof(uint), stream);
        edge_scatter_kernel<<<(NUM_P * NUM_E) / 4, 256, 0, stream>>>(
            xh, ei, logits, aggr_h);
        node_kernel<<<NUM_P * NUM_C * NB128, 128, 0, stream>>>(
            x, aggr_h, nwp, n2p, nb1, nb2, out);
    }
}